// Round 13
// baseline (236.076 us; speedup 1.0000x reference)
//
#include <hip/hip_runtime.h>

typedef __attribute__((ext_vector_type(8))) short short8;
typedef __attribute__((ext_vector_type(4))) float floatx4;
typedef __attribute__((ext_vector_type(4))) float float4v;
typedef __attribute__((ext_vector_type(4))) unsigned short ushort4v;

#define TILE_M 64
#define TILE_SHORTS (TILE_M * 256)   // 16384 shorts = 32 KB per buffer (flat, swizzled)
#define NBLOCKS 512                  // EXACTLY HW capacity: 2 blocks/CU x 256 CU (66.5 KB LDS)

static __device__ __forceinline__ unsigned short f2bf(float x) {
    unsigned int u = __builtin_bit_cast(unsigned int, x);
    unsigned int r = (u + 0x7FFFu + ((u >> 16) & 1u)) >> 16;
    return (unsigned short)r;
}

// async 16B global -> LDS (DMA, lands at lds_base + lane*16)
static __device__ __forceinline__ void gld16(const unsigned short* g, unsigned short* l) {
    __builtin_amdgcn_global_load_lds(
        (const __attribute__((address_space(1))) unsigned int*)g,
        (__attribute__((address_space(3))) unsigned int*)l, 16, 0, 0);
}

// ONE kernel, fused via manual grid barrier (cooperative launch fails in this harness):
//   Phase 0: grid-stride prep — tables fp32->bf16 (float4) + W1 transpose -> w1t
//   manual grid barrier (device-scope atomics in d_ws; counters memset to 0 per launch)
//   Phase 1: R8 pipeline (DMA double-buffer, ONE barrier per round):
//     barrier -> DMA(t+G) -> idx prefetch -> out(t-2G) -> reduce(t-G) -> K(t)
// Co-residency: grid == capacity (512 = 2/CU x 256), empty GPU -> no deadlock.
__global__ __launch_bounds__(256, 2) void edge_mlp(
    const float* __restrict__ zdf, const float* __restrict__ zsf,
    const int* __restrict__ row, const int* __restrict__ col,
    const float* __restrict__ W1,
    const float* __restrict__ b1, const float* __restrict__ w2,
    const float* __restrict__ b2, float* __restrict__ out,
    unsigned short* __restrict__ zd_b, unsigned short* __restrict__ zs_b,
    unsigned short* __restrict__ w1t, int* __restrict__ bar,
    int ntiles, int nd4, int ns4)
{
    __shared__ unsigned short lds_a[2][TILE_SHORTS];  // 64 KB double buffer
    __shared__ float red[2][2][TILE_M];               // 1 KB, slot = tile_index & 1

    const int tid  = threadIdx.x;

    // ================= Phase 0: prep (grid-stride) =================
    {
        const int gtid = blockIdx.x * 256 + tid;
        const int S = NBLOCKS * 256;                  // 131072 threads
        const int total4 = nd4 + ns4;
        const int jobs = total4 + 128 * 256;          // vec4 converts + W1 transpose
        for (int i = gtid; i < jobs; i += S) {
            if (i < total4) {
                const float* src; unsigned short* dst; int j;
                if (i < nd4) { src = zdf; dst = zd_b; j = i; }
                else         { src = zsf; dst = zs_b; j = i - nd4; }
                float4v v = *reinterpret_cast<const float4v*>(src + (size_t)j * 4);
                ushort4v o;
                o.x = f2bf(v.x); o.y = f2bf(v.y); o.z = f2bf(v.z); o.w = f2bf(v.w);
                *reinterpret_cast<ushort4v*>(dst + (size_t)j * 4) = o;
            } else {
                int j = i - total4;                   // 0..32767
                int n = j >> 8;
                int k = j & 255;
                w1t[n * 256 + k] = f2bf(W1[k * 128 + n]);
            }
        }
    }

    // ================= manual grid barrier =================
    __threadfence();                      // release: drain phase-0 stores to device scope
    __syncthreads();
    if (tid == 0) {
        if (atomicAdd(&bar[0], 1) == NBLOCKS - 1) {
            __hip_atomic_store(&bar[1], 1, __ATOMIC_RELEASE, __HIP_MEMORY_SCOPE_AGENT);
        } else {
            while (__hip_atomic_load(&bar[1], __ATOMIC_ACQUIRE, __HIP_MEMORY_SCOPE_AGENT) == 0)
                __builtin_amdgcn_s_sleep(8);
        }
    }
    __syncthreads();
    __threadfence();                      // acquire: invalidate stale L1/L2 views

    // ================= Phase 1: R8 main pipeline =================
    const unsigned short* zd = zd_b;
    const unsigned short* zs = zs_b;

    const int lane = tid & 63;
    const int wave = tid >> 6;
    const int wh   = wave >> 1;          // hidden half: [wh*64, wh*64+64)
    const int we   = wave & 1;           // edge half:   [we*32, we*32+32)
    const int l15  = lane & 15;
    const int quad = lane >> 4;
    const int whbase = wh * 64;

    // ---- persistent W1 A-fragments from w1t (128 regs, plain 16B loads) ----
    short8 wfrag[32];                    // [s*4 + mt]
    #pragma unroll
    for (int s = 0; s < 8; ++s)
        #pragma unroll
        for (int mt = 0; mt < 4; ++mt)
            wfrag[s * 4 + mt] = *reinterpret_cast<const short8*>(
                &w1t[(size_t)(whbase + mt * 16 + l15) * 256 + s * 32 + quad * 8]);

    // ---- persistent epilogue constants (32 regs) ----
    float4v b1v[4], w2v[4];
    #pragma unroll
    for (int mt = 0; mt < 4; ++mt) {
        b1v[mt] = *reinterpret_cast<const float4v*>(&b1[whbase + mt * 16 + quad * 4]);
        w2v[mt] = *reinterpret_cast<const float4v*>(&w2[whbase + mt * 16 + quad * 4]);
    }
    const float b2v = b2[0];

    // ---- fixed staging geometry for this thread ----
    const int e0 = tid >> 5;             // edges e0 + 8i
    const int jxw = tid & 31;            // physical chunk this thread fills
    const int jlog = jxw ^ (e0 & 7);     // logical k-chunk it fetches
    const unsigned short* tab = (jlog >= 16) ? zs : zd;
    const int* idxp = (jlog >= 16) ? col : row;
    const int koff = (jlog & 15) * 8;

    // reader swizzle constants
    const int hb = (l15 >> 2) & 1;
    const int qx = quad ^ (l15 & 3);

    const int G = NBLOCKS;
    const int R = ntiles / G;            // 16384/512 = 32, uniform
    const long t0 = blockIdx.x;

    // ---- prologue: DMA tile t0 into buf 0; prefetch indices for t0+G ----
    int nidx[8];
    #pragma unroll
    for (int i = 0; i < 8; ++i) nidx[i] = idxp[t0 * TILE_M + e0 + 8 * i];
    #pragma unroll
    for (int i = 0; i < 8; ++i)
        gld16(tab + (size_t)nidx[i] * 128 + koff, &lds_a[0][2048 * i + 512 * wave]);
    {
        long t1 = (R >= 2) ? (t0 + G) : t0;
        #pragma unroll
        for (int i = 0; i < 8; ++i) nidx[i] = idxp[t1 * TILE_M + e0 + 8 * i];
    }

    floatx4 acc[2][4];                   // [et][mt]

    for (int r = 0; r < R; ++r) {
        const long t = t0 + (long)r * G;

        // single barrier: drains DMA(t) into buf[r&1]; syncs red writes of round r-1
        __syncthreads();

        // (a) issue async DMA for tile t+G into the other buffer
        if (r + 1 < R) {
            #pragma unroll
            for (int i = 0; i < 8; ++i)
                gld16(tab + (size_t)nidx[i] * 128 + koff,
                      &lds_a[(r + 1) & 1][2048 * i + 512 * wave]);
        }
        // (b) prefetch indices for tile t+2G
        {
            long t2 = (r + 2 < R) ? (t0 + (long)(r + 2) * G) : t0;
            #pragma unroll
            for (int i = 0; i < 8; ++i) nidx[i] = idxp[t2 * TILE_M + e0 + 8 * i];
        }

        // (c) E2: out-write for tile t-2G (red slot r&1), spread over all 4 waves
        if (r >= 2 && lane < 16) {
            int eo = wave * 16 + l15;
            out[(t - 2 * G) * TILE_M + eo] =
                red[r & 1][0][eo] + red[r & 1][1][eo] + b2v;
        }

        // (d) E1: reduce acc of tile t-G into red slot (r-1)&1
        if (r >= 1) {
            const int slot = (r - 1) & 1;
            #pragma unroll
            for (int et = 0; et < 2; ++et) {
                float v = 0.f;
                #pragma unroll
                for (int mt = 0; mt < 4; ++mt)
                    #pragma unroll
                    for (int rr = 0; rr < 4; ++rr) {
                        float h = acc[et][mt][rr] + b1v[mt][rr];
                        h = h > 0.f ? h : 0.f;
                        v += h * w2v[mt][rr];
                    }
                v += __shfl_xor(v, 16);
                v += __shfl_xor(v, 32);
                if (lane < 16) red[slot][wh][we * 32 + et * 16 + l15] = v;
            }
        }

        // (e) K-loop: acc = W1half^T x Zhalf on buf[r&1]
        const unsigned short* buf = lds_a[r & 1];
        #pragma unroll
        for (int et = 0; et < 2; ++et)
            #pragma unroll
            for (int mt = 0; mt < 4; ++mt)
                acc[et][mt] = (floatx4)(0.0f);

        #pragma unroll
        for (int s = 0; s < 8; ++s) {
            const int sx = s ^ hb;
            short8 ef[2];
            #pragma unroll
            for (int et = 0; et < 2; ++et) {
                int e = we * 32 + et * 16 + l15;
                ef[et] = *reinterpret_cast<const short8*>(&buf[e * 256 + sx * 32 + qx * 8]);
            }
            #pragma unroll
            for (int et = 0; et < 2; ++et)
                #pragma unroll
                for (int mt = 0; mt < 4; ++mt)
                    acc[et][mt] = __builtin_amdgcn_mfma_f32_16x16x32_bf16(
                        wfrag[s * 4 + mt], ef[et], acc[et][mt], 0, 0, 0);
        }
    }

    // ---- pipeline drain ----
    __syncthreads();                     // syncs red writes of round R-1 (E1 of tile R-2)
    if (R >= 2 && lane < 16) {           // E2 for tile R-2 (slot R&1 == (R-2)&1)
        int eo = wave * 16 + l15;
        long tt = t0 + (long)(R - 2) * G;
        out[tt * TILE_M + eo] = red[R & 1][0][eo] + red[R & 1][1][eo] + b2v;
    }
    {                                    // E1 for tile R-1
        const int slot = (R - 1) & 1;
        #pragma unroll
        for (int et = 0; et < 2; ++et) {
            float v = 0.f;
            #pragma unroll
            for (int mt = 0; mt < 4; ++mt)
                #pragma unroll
                for (int rr = 0; rr < 4; ++rr) {
                    float h = acc[et][mt][rr] + b1v[mt][rr];
                    h = h > 0.f ? h : 0.f;
                    v += h * w2v[mt][rr];
                }
            v += __shfl_xor(v, 16);
            v += __shfl_xor(v, 32);
            if (lane < 16) red[slot][wh][we * 32 + et * 16 + l15] = v;
        }
    }
    __syncthreads();
    if (lane < 16) {                     // E2 for tile R-1
        int eo = wave * 16 + l15;
        long tt = t0 + (long)(R - 1) * G;
        out[tt * TILE_M + eo] = red[(R - 1) & 1][0][eo] + red[(R - 1) & 1][1][eo] + b2v;
    }
}

extern "C" void kernel_launch(void* const* d_in, const int* in_sizes, int n_in,
                              void* d_out, int out_size, void* d_ws, size_t ws_size,
                              hipStream_t stream) {
    const float* zd = (const float*)d_in[0];
    const float* zs = (const float*)d_in[1];
    const int*   row = (const int*)d_in[2];
    const int*   col = (const int*)d_in[3];
    const float* W1 = (const float*)d_in[4];
    const float* b1 = (const float*)d_in[5];
    const float* w2 = (const float*)d_in[6];
    const float* b2 = (const float*)d_in[7];
    float* out = (float*)d_out;

    const int nd = in_sizes[0];   // 10000*128
    const int ns = in_sizes[1];   // 15000*128
    const int E  = in_sizes[2];   // 1048576

    unsigned short* zd_b = (unsigned short*)d_ws;
    unsigned short* zs_b = zd_b + nd;
    unsigned short* w1t  = zs_b + ns;        // 128*256 bf16
    int* bar = (int*)(w1t + 128 * 256);      // 2 ints: arrive counter + release flag

    // reset the barrier words every launch (d_ws is re-poisoned to 0xAA by the harness)
    hipMemsetAsync(bar, 0, 16, stream);

    int ntiles = E / TILE_M;      // 16384
    int nd4 = nd / 4, ns4 = ns / 4;

    hipLaunchKernelGGL(edge_mlp, dim3(NBLOCKS), dim3(256), 0, stream,
                       zd, zs, row, col, W1, b1, w2, b2, out,
                       zd_b, zs_b, w1t, bar, ntiles, nd4, ns4);
}